// Round 1
// baseline (682.697 us; speedup 1.0000x reference)
//
#include <hip/hip_runtime.h>

// Problem constants
#define NB 4
#define NC 64
#define NH 64
#define NW 64
#define NN 4096   // NH*NW

// workspace layout (float offsets)
#define OFF_Q     0u
#define OFF_K     1048576u
#define OFF_V     2097152u
#define OFF_POS   3145728u
#define OFF_WT    4194304u                 // 3 * 36864 transposed weights
#define OFF_MPART (OFF_WT + 110592u)       // 4 * 4 * 4096
#define OFF_LPART (OFF_MPART + 65536u)
#define OFF_M     (OFF_LPART + 65536u)     // 4*4096
#define OFF_INVL  (OFF_M + 16384u)
#define OFF_GPART (OFF_INVL + 16384u)      // 16 * 4 * 64 * 64
#define OFF_A     (OFF_GPART + 262144u)
#define WS_FLOATS (OFF_A + 16384u)

// ---------------- weight transpose: w[o][ci][3][3] -> wt[conv][ci*9+tap][o]
__global__ void k_wtrans(const float* __restrict__ wq, const float* __restrict__ wk,
                         const float* __restrict__ wv, float* __restrict__ wt) {
    int idx = blockIdx.x * 256 + threadIdx.x;     // < 3*36864
    int conv = idx / 36864;
    int r = idx % 36864;
    int o = r & 63;
    int t2 = r >> 6;            // ci*9+tap
    int ci = t2 / 9, tap = t2 % 9;
    const float* w = (conv == 0) ? wq : (conv == 1) ? wk : wv;
    wt[idx] = w[(o * 64 + ci) * 9 + tap];
}

// ---------------- fused 3x3 conv (SAME), one (b,h) row, all 64 o, all 64 w
__global__ __launch_bounds__(256) void k_conv(
        const float* __restrict__ x, const float* __restrict__ wt,
        const float* __restrict__ bq, const float* __restrict__ bk, const float* __restrict__ bv,
        float* __restrict__ q, float* __restrict__ k, float* __restrict__ v) {
    int h = blockIdx.x, b = blockIdx.y, conv = blockIdx.z;
    const float* bias = (conv == 0) ? bq : (conv == 1) ? bk : bv;
    float* out = (conv == 0) ? q : (conv == 1) ? k : v;
    const float* wtc = wt + conv * 36864;

    __shared__ float xch[16 * 3 * 66];   // [cil][dy][col], col 0 & 65 are zero pad
    __shared__ float wch[16 * 9 * 64];   // [cil][tap][o]

    int tid = threadIdx.x;
    int wtd = tid & 15, ot = tid >> 4;   // 16 w-groups x 16 o-groups
    int w0 = wtd * 4, o0 = ot * 4;

    float acc[4][4];
    {
        float4 b4 = *(const float4*)(bias + o0);
        float bb[4] = {b4.x, b4.y, b4.z, b4.w};
#pragma unroll
        for (int oo = 0; oo < 4; ++oo)
#pragma unroll
            for (int ww = 0; ww < 4; ++ww) acc[oo][ww] = bb[oo];
    }

    for (int ck = 0; ck < 4; ++ck) {
        __syncthreads();
        // stage x rows h-1..h+1 for 16 channels, zero-padded
        for (int idx = tid; idx < 3168; idx += 256) {
            int col = idx % 66;
            int row = idx / 66;
            int dy = row % 3, cil = row / 3;
            int ci = ck * 16 + cil;
            int hs = h + dy - 1;
            float val = 0.0f;
            if (col >= 1 && col <= 64 && hs >= 0 && hs < 64)
                val = x[((b * 64 + ci) * 64 + hs) * 64 + (col - 1)];
            xch[(cil * 3 + dy) * 66 + col] = val;
        }
        // stage weights chunk (contiguous)
        for (int idx = tid; idx < 2304; idx += 256)
            ((float4*)wch)[idx] = ((const float4*)(wtc + ck * 9216))[idx];
        __syncthreads();

        for (int cil = 0; cil < 16; ++cil) {
#pragma unroll
            for (int dy = 0; dy < 3; ++dy) {
                float xv[6];
#pragma unroll
                for (int s = 0; s < 6; ++s) xv[s] = xch[(cil * 3 + dy) * 66 + w0 + s];
#pragma unroll
                for (int dx = 0; dx < 3; ++dx) {
                    float4 w4 = ((const float4*)wch)[(cil * 9 + dy * 3 + dx) * 16 + ot];
                    float wa[4] = {w4.x, w4.y, w4.z, w4.w};
#pragma unroll
                    for (int oo = 0; oo < 4; ++oo)
#pragma unroll
                        for (int ww = 0; ww < 4; ++ww)
                            acc[oo][ww] += xv[ww + dx] * wa[oo];
                }
            }
        }
    }
#pragma unroll
    for (int oo = 0; oo < 4; ++oo) {
        float4 o4 = {acc[oo][0], acc[oo][1], acc[oo][2], acc[oo][3]};
        *(float4*)(out + ((b * 64 + o0 + oo) * 64 + h) * 64 + w0) = o4;
    }
}

// ---------------- channel Gram partials: Gpart[nc][b][c][d] over 256-n chunk
__global__ __launch_bounds__(256) void k_gram(const float* __restrict__ x, float* __restrict__ Gpart) {
    int nc = blockIdx.x, b = blockIdx.y;
    __shared__ float xs[64 * 257];
    int tid = threadIdx.x;
    for (int it = 0; it < 16; ++it) {
        int f4i = tid + it * 256;
        int c = f4i >> 6, n4 = f4i & 63;
        float4 vv = *(const float4*)(x + (b * 64 + c) * 4096 + nc * 256 + n4 * 4);
        xs[c * 257 + n4 * 4 + 0] = vv.x;
        xs[c * 257 + n4 * 4 + 1] = vv.y;
        xs[c * 257 + n4 * 4 + 2] = vv.z;
        xs[c * 257 + n4 * 4 + 3] = vv.w;
    }
    __syncthreads();
    int tc = tid & 15, td = tid >> 4;
    int c0 = tc * 4, d0 = td * 4;
    float acc[4][4];
#pragma unroll
    for (int i = 0; i < 4; ++i)
#pragma unroll
        for (int j = 0; j < 4; ++j) acc[i][j] = 0.0f;
    for (int n = 0; n < 256; ++n) {
        float xc[4], xd[4];
#pragma unroll
        for (int i = 0; i < 4; ++i) xc[i] = xs[(c0 + i) * 257 + n];
#pragma unroll
        for (int j = 0; j < 4; ++j) xd[j] = xs[(d0 + j) * 257 + n];
#pragma unroll
        for (int i = 0; i < 4; ++i)
#pragma unroll
            for (int j = 0; j < 4; ++j) acc[i][j] += xc[i] * xd[j];
    }
#pragma unroll
    for (int i = 0; i < 4; ++i) {
        float4 o4 = {acc[i][0], acc[i][1], acc[i][2], acc[i][3]};
        *(float4*)(Gpart + ((nc * 4 + b) * 64 + c0 + i) * 64 + d0) = o4;
    }
}

// ---------------- channel softmax rows (one wave per row)
__global__ void k_asm(const float* __restrict__ Gpart, float* __restrict__ A) {
    int row = blockIdx.x;      // b*64 + c
    int d = threadIdx.x;
    int b = row >> 6, c = row & 63;
    float g = 0.0f;
    for (int p = 0; p < 16; ++p) g += Gpart[(p * 4 + b) * 4096 + c * 64 + d];
    float mx = g;
    for (int off = 32; off >= 1; off >>= 1) mx = fmaxf(mx, __shfl_xor(mx, off, 64));
    float e = __expf(g - mx);
    float s = e;
    for (int off = 32; off >= 1; off >>= 1) s += __shfl_xor(s, off, 64);
    A[row * 64 + d] = e / s;
}

// ---------------- pass1: row stats (m,l) over a quarter of j, i-tile 64
__global__ __launch_bounds__(256) void k_pass1(const float* __restrict__ q, const float* __restrict__ kk,
                                               float* __restrict__ mpart, float* __restrict__ lpart) {
    // XCD swizzle: each XCD-pair owns one batch
    int flat = blockIdx.x + 64 * (blockIdx.y + 4 * blockIdx.z);   // 0..1023
    int xcd = flat & 7, slot = flat >> 3;                         // slot 0..127
    int b = xcd >> 1;
    int rem = (xcd & 1) * 128 + slot;                             // 0..255
    int itile = rem & 63, jp = rem >> 6;

    __shared__ float qs[64 * 64];    // [c][i]
    __shared__ float ks[64 * 128];   // [c][j]
    int tid = threadIdx.x;
    int i0g = itile * 64;

    for (int it2 = 0; it2 < 4; ++it2) {
        int f4i = tid + it2 * 256;
        int c = f4i >> 4, i4 = f4i & 15;
        *(float4*)(qs + c * 64 + i4 * 4) = *(const float4*)(q + (b * 64 + c) * 4096 + i0g + i4 * 4);
    }

    int ti = tid & 15, tj = tid >> 4;
    float m[4] = {-1e30f, -1e30f, -1e30f, -1e30f};
    float l[4] = {0.0f, 0.0f, 0.0f, 0.0f};

    for (int jt = 0; jt < 8; ++jt) {
        int j0g = jp * 1024 + jt * 128;
        __syncthreads();
        for (int it2 = 0; it2 < 8; ++it2) {
            int f4i = tid + it2 * 256;
            int c = f4i >> 5, j4 = f4i & 31;
            *(float4*)(ks + c * 128 + j4 * 4) = *(const float4*)(kk + (b * 64 + c) * 4096 + j0g + j4 * 4);
        }
        __syncthreads();

        float s[4][8];
#pragma unroll
        for (int r = 0; r < 4; ++r)
#pragma unroll
            for (int u = 0; u < 8; ++u) s[r][u] = 0.0f;

        for (int c = 0; c < 64; ++c) {
            float4 q4 = *(const float4*)(qs + c * 64 + ti * 4);
            float4 ka = *(const float4*)(ks + c * 128 + tj * 8);
            float4 kb = *(const float4*)(ks + c * 128 + tj * 8 + 4);
            float qa[4] = {q4.x, q4.y, q4.z, q4.w};
            float kv[8] = {ka.x, ka.y, ka.z, ka.w, kb.x, kb.y, kb.z, kb.w};
#pragma unroll
            for (int r = 0; r < 4; ++r)
#pragma unroll
                for (int u = 0; u < 8; ++u) s[r][u] += qa[r] * kv[u];
        }
#pragma unroll
        for (int r = 0; r < 4; ++r) {
            float mt = s[r][0];
#pragma unroll
            for (int u = 1; u < 8; ++u) mt = fmaxf(mt, s[r][u]);
            float mn = fmaxf(m[r], mt);
            float add = 0.0f;
#pragma unroll
            for (int u = 0; u < 8; ++u) add += __expf(s[r][u] - mn);
            l[r] = l[r] * __expf(m[r] - mn) + add;
            m[r] = mn;
        }
    }

    __syncthreads();
    float2* ml = (float2*)qs;   // reuse
#pragma unroll
    for (int r = 0; r < 4; ++r) ml[(ti * 4 + r) * 16 + tj] = {m[r], l[r]};
    __syncthreads();
    if (tid < 64) {
        float mm = -1e30f;
        for (int t = 0; t < 16; ++t) mm = fmaxf(mm, ml[tid * 16 + t].x);
        float ll = 0.0f;
        for (int t = 0; t < 16; ++t) ll += ml[tid * 16 + t].y * __expf(ml[tid * 16 + t].x - mm);
        mpart[(jp * 4 + b) * 4096 + i0g + tid] = mm;
        lpart[(jp * 4 + b) * 4096 + i0g + tid] = ll;
    }
}

// ---------------- merge 4 j-partials -> m, 1/l
__global__ void k_merge(const float* __restrict__ mpart, const float* __restrict__ lpart,
                        float* __restrict__ mrow, float* __restrict__ invl) {
    int idx = blockIdx.x * 256 + threadIdx.x;   // b*4096 + i
    float mm = -1e30f;
#pragma unroll
    for (int p = 0; p < 4; ++p) mm = fmaxf(mm, mpart[p * 16384 + idx]);
    float ll = 0.0f;
#pragma unroll
    for (int p = 0; p < 4; ++p) ll += lpart[p * 16384 + idx] * __expf(mpart[p * 16384 + idx] - mm);
    mrow[idx] = mm;
    invl[idx] = 1.0f / ll;
}

// ---------------- pass2: pos[c,j] = sum_i exp(s_ij - m_i) * (v[c,i]/l_i)
__global__ __launch_bounds__(256) void k_pass2(const float* __restrict__ q, const float* __restrict__ kk,
                                               const float* __restrict__ v, const float* __restrict__ mrow,
                                               const float* __restrict__ invl, float* __restrict__ pos) {
    int flat = blockIdx.x + 128 * blockIdx.y;    // 0..511
    int xcd = flat & 7, slot = flat >> 3;        // slot 0..63
    int b = xcd >> 1;
    int jt = (xcd & 1) * 64 + slot;              // 0..127
    int j0g = jt * 32;

    __shared__ float ks[64 * 32];   // [c][j]
    __shared__ float qs[64 * 64];   // [c][i]
    __shared__ float vs[64 * 64];   // [i][c]  (v * invl)
    __shared__ float ps[64 * 32];   // [i][j]
    __shared__ float ms[64];

    int tid = threadIdx.x;
    for (int it2 = 0; it2 < 2; ++it2) {
        int f4i = tid + it2 * 256;
        int c = f4i >> 3, j4 = f4i & 7;
        *(float4*)(ks + c * 32 + j4 * 4) = *(const float4*)(kk + (b * 64 + c) * 4096 + j0g + j4 * 4);
    }

    int t0 = tid & 15, t1 = tid >> 4;
    float oa[4][2];
#pragma unroll
    for (int cc = 0; cc < 4; ++cc) { oa[cc][0] = 0.0f; oa[cc][1] = 0.0f; }

    for (int itile = 0; itile < 64; ++itile) {
        int i0g = itile * 64;
        __syncthreads();   // previous iter done reading qs/vs/ps
        for (int it2 = 0; it2 < 4; ++it2) {
            int f4i = tid + it2 * 256;
            int c = f4i >> 4, i4 = f4i & 15;
            *(float4*)(qs + c * 64 + i4 * 4) = *(const float4*)(q + (b * 64 + c) * 4096 + i0g + i4 * 4);
            float4 vv = *(const float4*)(v + (b * 64 + c) * 4096 + i0g + i4 * 4);
            float4 iv = *(const float4*)(invl + b * 4096 + i0g + i4 * 4);
            vs[(i4 * 4 + 0) * 64 + c] = vv.x * iv.x;
            vs[(i4 * 4 + 1) * 64 + c] = vv.y * iv.y;
            vs[(i4 * 4 + 2) * 64 + c] = vv.z * iv.z;
            vs[(i4 * 4 + 3) * 64 + c] = vv.w * iv.w;
        }
        if (tid < 16) *(float4*)(ms + tid * 4) = *(const float4*)(mrow + b * 4096 + i0g + tid * 4);
        __syncthreads();

        float mr[4];
#pragma unroll
        for (int r = 0; r < 4; ++r) mr[r] = ms[t0 * 4 + r];

        float s[4][2];
#pragma unroll
        for (int r = 0; r < 4; ++r) { s[r][0] = 0.0f; s[r][1] = 0.0f; }
        for (int c = 0; c < 64; ++c) {
            float4 q4 = *(const float4*)(qs + c * 64 + t0 * 4);
            float2 k2 = *(const float2*)(ks + c * 32 + t1 * 2);
            float qa[4] = {q4.x, q4.y, q4.z, q4.w};
#pragma unroll
            for (int r = 0; r < 4; ++r) {
                s[r][0] += qa[r] * k2.x;
                s[r][1] += qa[r] * k2.y;
            }
        }
#pragma unroll
        for (int r = 0; r < 4; ++r) {
            float2 pw = {__expf(s[r][0] - mr[r]), __expf(s[r][1] - mr[r])};
            *(float2*)(ps + (t0 * 4 + r) * 32 + t1 * 2) = pw;
        }
        __syncthreads();

        for (int i = 0; i < 64; ++i) {
            float4 v4 = *(const float4*)(vs + i * 64 + t0 * 4);
            float2 p2 = *(const float2*)(ps + i * 32 + t1 * 2);
            float va[4] = {v4.x, v4.y, v4.z, v4.w};
#pragma unroll
            for (int cc = 0; cc < 4; ++cc) {
                oa[cc][0] += va[cc] * p2.x;
                oa[cc][1] += va[cc] * p2.y;
            }
        }
    }
#pragma unroll
    for (int cc = 0; cc < 4; ++cc) {
        float2 o2 = {oa[cc][0], oa[cc][1]};
        *(float2*)(pos + (b * 64 + t0 * 4 + cc) * 4096 + j0g + t1 * 2) = o2;
    }
}

// ---------------- final: out = pg*pos + cg*(A@x) + 2*x
__global__ void k_final(const float* __restrict__ x, const float* __restrict__ pos,
                        const float* __restrict__ A, const float* __restrict__ pg,
                        const float* __restrict__ cg, float* __restrict__ out) {
    int n = blockIdx.x * 256 + threadIdx.x;
    int c = blockIdx.y, b = blockIdx.z;
    const float* Arow = A + (b * 64 + c) * 64;
    const float* xb = x + b * 64 * 4096;
    float acc = 0.0f;
#pragma unroll
    for (int d = 0; d < 64; ++d) acc += Arow[d] * xb[d * 4096 + n];
    float xc = xb[c * 4096 + n];
    float p = pos[(b * 64 + c) * 4096 + n];
    out[(b * 64 + c) * 4096 + n] = pg[0] * p + cg[0] * acc + 2.0f * xc;
}

extern "C" void kernel_launch(void* const* d_in, const int* in_sizes, int n_in,
                              void* d_out, int out_size, void* d_ws, size_t ws_size,
                              hipStream_t stream) {
    const float* x  = (const float*)d_in[0];
    const float* wq = (const float*)d_in[1];
    const float* bq = (const float*)d_in[2];
    const float* wk = (const float*)d_in[3];
    const float* bk = (const float*)d_in[4];
    const float* wv = (const float*)d_in[5];
    const float* bv = (const float*)d_in[6];
    const float* pg = (const float*)d_in[7];
    const float* cg = (const float*)d_in[8];
    float* out = (float*)d_out;

    if (ws_size < (size_t)WS_FLOATS * sizeof(float)) return;
    float* ws = (float*)d_ws;
    float* q    = ws + OFF_Q;
    float* k    = ws + OFF_K;
    float* v    = ws + OFF_V;
    float* pos  = ws + OFF_POS;
    float* wt   = ws + OFF_WT;
    float* mp   = ws + OFF_MPART;
    float* lp   = ws + OFF_LPART;
    float* mrow = ws + OFF_M;
    float* invl = ws + OFF_INVL;
    float* Gp   = ws + OFF_GPART;
    float* A    = ws + OFF_A;

    k_wtrans<<<432, 256, 0, stream>>>(wq, wk, wv, wt);
    k_conv<<<dim3(64, 4, 3), 256, 0, stream>>>(x, wt, bq, bk, bv, q, k, v);
    k_gram<<<dim3(16, 4), 256, 0, stream>>>(x, Gp);
    k_asm<<<256, 64, 0, stream>>>(Gp, A);
    k_pass1<<<dim3(64, 4, 4), 256, 0, stream>>>(q, k, mp, lp);
    k_merge<<<64, 256, 0, stream>>>(mp, lp, mrow, invl);
    k_pass2<<<dim3(128, 4), 256, 0, stream>>>(q, k, v, mrow, invl, pos);
    k_final<<<dim3(16, 64, 4), 256, 0, stream>>>(x, pos, A, pg, cg, out);
}

// Round 2
// 331.318 us; speedup vs baseline: 2.0605x; 2.0605x over previous
//
#include <hip/hip_runtime.h>

// Problem constants: B=4, C=64, H=W=64, N=4096
// Workspace layout (float offsets) — total 4,747,264 floats, identical to the
// round-1 footprint that is proven to fit ws_size.
#define OFF_POS   0u
#define OFF_QTH   1048576u
#define OFF_QTL   1572864u
#define OFF_KTH   2097152u
#define OFF_KTL   2621440u
#define OFF_VBH   3145728u
#define OFF_VBL   3670016u
#define OFF_WT    4194304u
#define OFF_MPART 4304896u
#define OFF_LPART 4370432u
#define OFF_M     4435968u
#define OFF_INVL  4452352u
#define OFF_GPART 4468736u
#define OFF_A     4730880u
#define WS_FLOATS 4747264u

typedef short s8v __attribute__((ext_vector_type(8)));
typedef float f4v __attribute__((ext_vector_type(4)));

#define MFMA16(a, b, c) __builtin_amdgcn_mfma_f32_16x16x32_bf16((a), (b), (c), 0, 0, 0)

__device__ __forceinline__ unsigned short bf16_rne(float f) {
    union { float f; unsigned int u; } v; v.f = f;
    unsigned int r = v.u + 0x7FFFu + ((v.u >> 16) & 1u);
    return (unsigned short)(r >> 16);
}
__device__ __forceinline__ void split2(float f, unsigned short& h, unsigned short& l) {
    unsigned short hh = bf16_rne(f);
    union { unsigned int u; float f; } b; b.u = ((unsigned int)hh) << 16;
    h = hh;
    l = bf16_rne(f - b.f);
}

// ---------------- weight transpose: w[o][ci][3][3] -> wt[conv][ci*9+tap][o]
__global__ void k_wtrans(const float* __restrict__ wq, const float* __restrict__ wk,
                         const float* __restrict__ wv, float* __restrict__ wt) {
    int idx = blockIdx.x * 256 + threadIdx.x;     // < 3*36864
    int conv = idx / 36864;
    int r = idx % 36864;
    int o = r & 63;
    int t2 = r >> 6;            // ci*9+tap
    int ci = t2 / 9, tap = t2 % 9;
    const float* w = (conv == 0) ? wq : (conv == 1) ? wk : wv;
    wt[idx] = w[(o * 64 + ci) * 9 + tap];
}

// ---------------- fused 3x3 conv (SAME) writing split-bf16 outputs:
//   q,k -> transposed [b][n][c] hi/lo arrays (for MFMA A/B fragment loads)
//   v   -> blocked [b][cb][n8][cc][e] hi/lo (c=cb*16+cc, n=n8*8+e)
__global__ __launch_bounds__(256) void k_conv(
        const float* __restrict__ x, const float* __restrict__ wt,
        const float* __restrict__ bq, const float* __restrict__ bk, const float* __restrict__ bv,
        unsigned short* __restrict__ qth, unsigned short* __restrict__ qtl,
        unsigned short* __restrict__ kth, unsigned short* __restrict__ ktl,
        unsigned short* __restrict__ vbh, unsigned short* __restrict__ vbl) {
    int h = blockIdx.x, b = blockIdx.y, conv = blockIdx.z;
    const float* bias = (conv == 0) ? bq : (conv == 1) ? bk : bv;
    const float* wtc = wt + conv * 36864;

    __shared__ float xch[16 * 3 * 66];   // [cil][dy][col], col 0 & 65 zero pad
    __shared__ float wch[16 * 9 * 64];   // [cil][tap][o]

    int tid = threadIdx.x;
    int wtd = tid & 15, ot = tid >> 4;
    int w0 = wtd * 4, o0 = ot * 4;

    float acc[4][4];
    {
        float4 b4 = *(const float4*)(bias + o0);
        float bb[4] = {b4.x, b4.y, b4.z, b4.w};
#pragma unroll
        for (int oo = 0; oo < 4; ++oo)
#pragma unroll
            for (int ww = 0; ww < 4; ++ww) acc[oo][ww] = bb[oo];
    }

    for (int ck = 0; ck < 4; ++ck) {
        __syncthreads();
        for (int idx = tid; idx < 3168; idx += 256) {
            int col = idx % 66;
            int row = idx / 66;
            int dy = row % 3, cil = row / 3;
            int ci = ck * 16 + cil;
            int hs = h + dy - 1;
            float val = 0.0f;
            if (col >= 1 && col <= 64 && hs >= 0 && hs < 64)
                val = x[((b * 64 + ci) * 64 + hs) * 64 + (col - 1)];
            xch[(cil * 3 + dy) * 66 + col] = val;
        }
        for (int idx = tid; idx < 2304; idx += 256)
            ((float4*)wch)[idx] = ((const float4*)(wtc + ck * 9216))[idx];
        __syncthreads();

        for (int cil = 0; cil < 16; ++cil) {
#pragma unroll
            for (int dy = 0; dy < 3; ++dy) {
                float xv[6];
#pragma unroll
                for (int s = 0; s < 6; ++s) xv[s] = xch[(cil * 3 + dy) * 66 + w0 + s];
#pragma unroll
                for (int dx = 0; dx < 3; ++dx) {
                    float4 w4 = ((const float4*)wch)[(cil * 9 + dy * 3 + dx) * 16 + ot];
                    float wa[4] = {w4.x, w4.y, w4.z, w4.w};
#pragma unroll
                    for (int oo = 0; oo < 4; ++oo)
#pragma unroll
                        for (int ww = 0; ww < 4; ++ww)
                            acc[oo][ww] += xv[ww + dx] * wa[oo];
                }
            }
        }
    }

    if (conv < 2) {
        unsigned short* oh = (conv == 0) ? qth : kth;
        unsigned short* ol = (conv == 0) ? qtl : ktl;
#pragma unroll
        for (int ww = 0; ww < 4; ++ww) {
            unsigned short h4[4], l4[4];
#pragma unroll
            for (int oo = 0; oo < 4; ++oo) split2(acc[oo][ww], h4[oo], l4[oo]);
            int ad = (b * 4096 + h * 64 + w0 + ww) * 64 + o0;
            uint2 hv, lv;
            hv.x = h4[0] | ((unsigned int)h4[1] << 16);
            hv.y = h4[2] | ((unsigned int)h4[3] << 16);
            lv.x = l4[0] | ((unsigned int)l4[1] << 16);
            lv.y = l4[2] | ((unsigned int)l4[3] << 16);
            *(uint2*)(oh + ad) = hv;
            *(uint2*)(ol + ad) = lv;
        }
    } else {
        int cb = o0 >> 4, ccb = o0 & 15;
#pragma unroll
        for (int ww = 0; ww < 4; ++ww) {
            int n = h * 64 + w0 + ww;
            int n8 = n >> 3, e = n & 7;
            int basead = ((b * 4 + cb) * 512 + n8) * 16;
#pragma unroll
            for (int oo = 0; oo < 4; ++oo) {
                unsigned short hh, ll;
                split2(acc[oo][ww], hh, ll);
                vbh[(basead + ccb + oo) * 8 + e] = hh;
                vbl[(basead + ccb + oo) * 8 + e] = ll;
            }
        }
    }
}

// ---------------- channel Gram partials (unchanged)
__global__ __launch_bounds__(256) void k_gram(const float* __restrict__ x, float* __restrict__ Gpart) {
    int nc = blockIdx.x, b = blockIdx.y;
    __shared__ float xs[64 * 257];
    int tid = threadIdx.x;
    for (int it = 0; it < 16; ++it) {
        int f4i = tid + it * 256;
        int c = f4i >> 6, n4 = f4i & 63;
        float4 vv = *(const float4*)(x + (b * 64 + c) * 4096 + nc * 256 + n4 * 4);
        xs[c * 257 + n4 * 4 + 0] = vv.x;
        xs[c * 257 + n4 * 4 + 1] = vv.y;
        xs[c * 257 + n4 * 4 + 2] = vv.z;
        xs[c * 257 + n4 * 4 + 3] = vv.w;
    }
    __syncthreads();
    int tc = tid & 15, td = tid >> 4;
    int c0 = tc * 4, d0 = td * 4;
    float acc[4][4];
#pragma unroll
    for (int i = 0; i < 4; ++i)
#pragma unroll
        for (int j = 0; j < 4; ++j) acc[i][j] = 0.0f;
    for (int n = 0; n < 256; ++n) {
        float xc[4], xd[4];
#pragma unroll
        for (int i = 0; i < 4; ++i) xc[i] = xs[(c0 + i) * 257 + n];
#pragma unroll
        for (int j = 0; j < 4; ++j) xd[j] = xs[(d0 + j) * 257 + n];
#pragma unroll
        for (int i = 0; i < 4; ++i)
#pragma unroll
            for (int j = 0; j < 4; ++j) acc[i][j] += xc[i] * xd[j];
    }
#pragma unroll
    for (int i = 0; i < 4; ++i) {
        float4 o4 = {acc[i][0], acc[i][1], acc[i][2], acc[i][3]};
        *(float4*)(Gpart + ((nc * 4 + b) * 64 + c0 + i) * 64 + d0) = o4;
    }
}

// ---------------- channel softmax rows (unchanged)
__global__ void k_asm(const float* __restrict__ Gpart, float* __restrict__ A) {
    int row = blockIdx.x;      // b*64 + c
    int d = threadIdx.x;
    int b = row >> 6, c = row & 63;
    float g = 0.0f;
    for (int p = 0; p < 16; ++p) g += Gpart[(p * 4 + b) * 4096 + c * 64 + d];
    float mx = g;
    for (int off = 32; off >= 1; off >>= 1) mx = fmaxf(mx, __shfl_xor(mx, off, 64));
    float e = __expf(g - mx);
    float s = e;
    for (int off = 32; off >= 1; off >>= 1) s += __shfl_xor(s, off, 64);
    A[row * 64 + d] = e / s;
}

// ---------------- pass1: MFMA QK^T row stats over a quarter of j
// grid 1024 = (64,4,4); block 256 (4 waves), wave = 16-row i-strip.
// Fragments read directly from L2 (no LDS, no barriers).
__global__ __launch_bounds__(256) void k_pass1(
        const unsigned short* __restrict__ qth, const unsigned short* __restrict__ qtl,
        const unsigned short* __restrict__ kth, const unsigned short* __restrict__ ktl,
        float* __restrict__ mpart, float* __restrict__ lpart) {
    int flat = blockIdx.x + 64 * (blockIdx.y + 4 * blockIdx.z);   // 0..1023
    int xcd = flat & 7, slot = flat >> 3;
    int b = xcd >> 1;
    int rem = (xcd & 1) * 128 + slot;     // 0..255
    int itile = rem & 63, jp = rem >> 6;

    int tid = threadIdx.x;
    int lane = tid & 63, wv = tid >> 6;
    int l15 = lane & 15, g = lane >> 4;
    int i0 = itile * 64 + wv * 16;

    int qb = (b * 4096 + i0 + l15) * 64 + g * 8;
    s8v qa00 = *(const s8v*)(qth + qb);        // hi, c-chunk 0
    s8v qa01 = *(const s8v*)(qtl + qb);        // lo, c-chunk 0
    s8v qa10 = *(const s8v*)(qth + qb + 32);   // hi, c-chunk 1
    s8v qa11 = *(const s8v*)(qtl + qb + 32);   // lo, c-chunk 1

    float m[4] = {-1e30f, -1e30f, -1e30f, -1e30f};
    float l[4] = {0.f, 0.f, 0.f, 0.f};

    for (int jt = 0; jt < 16; ++jt) {
        int j0 = jp * 1024 + jt * 64;
        f4v S[4];
#pragma unroll
        for (int js = 0; js < 4; ++js) {
            int kb = (b * 4096 + j0 + js * 16 + l15) * 64 + g * 8;
            s8v bh0 = *(const s8v*)(kth + kb);
            s8v bl0 = *(const s8v*)(ktl + kb);
            s8v bh1 = *(const s8v*)(kth + kb + 32);
            s8v bl1 = *(const s8v*)(ktl + kb + 32);
            f4v acc = {0.f, 0.f, 0.f, 0.f};
            acc = MFMA16(qa00, bh0, acc);
            acc = MFMA16(qa00, bl0, acc);
            acc = MFMA16(qa01, bh0, acc);
            acc = MFMA16(qa10, bh1, acc);
            acc = MFMA16(qa10, bl1, acc);
            acc = MFMA16(qa11, bh1, acc);
            S[js] = acc;
        }
#pragma unroll
        for (int r = 0; r < 4; ++r) {
            float mt = fmaxf(fmaxf(S[0][r], S[1][r]), fmaxf(S[2][r], S[3][r]));
            mt = fmaxf(mt, __shfl_xor(mt, 1));
            mt = fmaxf(mt, __shfl_xor(mt, 2));
            mt = fmaxf(mt, __shfl_xor(mt, 4));
            mt = fmaxf(mt, __shfl_xor(mt, 8));
            float mn = fmaxf(m[r], mt);
            float ad = __expf(S[0][r] - mn) + __expf(S[1][r] - mn)
                     + __expf(S[2][r] - mn) + __expf(S[3][r] - mn);
            ad += __shfl_xor(ad, 1);
            ad += __shfl_xor(ad, 2);
            ad += __shfl_xor(ad, 4);
            ad += __shfl_xor(ad, 8);
            l[r] = l[r] * __expf(m[r] - mn) + ad;
            m[r] = mn;
        }
    }
    if (l15 == 0) {
        int ib = (jp * 4 + b) * 4096 + i0 + g * 4;
#pragma unroll
        for (int r = 0; r < 4; ++r) {
            mpart[ib + r] = m[r];
            lpart[ib + r] = l[r];
        }
    }
}

// ---------------- merge 4 j-partials -> m, 1/l (unchanged)
__global__ void k_merge(const float* __restrict__ mpart, const float* __restrict__ lpart,
                        float* __restrict__ mrow, float* __restrict__ invl) {
    int idx = blockIdx.x * 256 + threadIdx.x;
    float mm = -1e30f;
#pragma unroll
    for (int p = 0; p < 4; ++p) mm = fmaxf(mm, mpart[p * 16384 + idx]);
    float ll = 0.0f;
#pragma unroll
    for (int p = 0; p < 4; ++p) ll += lpart[p * 16384 + idx] * __expf(mpart[p * 16384 + idx] - mm);
    mrow[idx] = mm;
    invl[idx] = 1.0f / ll;
}

// ---------------- pass2: MFMA flash pass. grid 256, block 512 (8 waves).
// Block owns (b, 64-col j-tile); loops i in steps of 128.
// QK: wave = 16-row i-strip (K-frags for all 64 j held in registers).
// P staged hi/lo in LDS; PV: wave = (c-quarter 16, j-half 32).
__global__ __launch_bounds__(512) void k_pass2(
        const unsigned short* __restrict__ qth, const unsigned short* __restrict__ qtl,
        const unsigned short* __restrict__ kth, const unsigned short* __restrict__ ktl,
        const unsigned short* __restrict__ vbh, const unsigned short* __restrict__ vbl,
        const float* __restrict__ mrow, const float* __restrict__ invl,
        float* __restrict__ pos) {
    int flat = blockIdx.x;
    int xcd = flat & 7;
    int b = xcd >> 1;
    int jt = (xcd & 1) * 32 + (flat >> 3);
    int j0 = jt * 64;

    int tid = threadIdx.x;
    int lane = tid & 63, wv = tid >> 6;
    int l15 = lane & 15, g = lane >> 4;

    __shared__ unsigned short Ph[64][136];
    __shared__ unsigned short Pl[64][136];

    // K fragments for all 64 j, held in registers: [jsub][cchunk][hi/lo]
    s8v kf[4][2][2];
#pragma unroll
    for (int js = 0; js < 4; ++js) {
        int kb = (b * 4096 + j0 + js * 16 + l15) * 64 + g * 8;
        kf[js][0][0] = *(const s8v*)(kth + kb);
        kf[js][0][1] = *(const s8v*)(ktl + kb);
        kf[js][1][0] = *(const s8v*)(kth + kb + 32);
        kf[js][1][1] = *(const s8v*)(ktl + kb + 32);
    }

    int cq = wv & 3, jh = wv >> 2;
    f4v oa = {0.f, 0.f, 0.f, 0.f};
    f4v ob = {0.f, 0.f, 0.f, 0.f};

    for (int it = 0; it < 32; ++it) {
        int i0 = it * 128;
        int iw = i0 + wv * 16;
        int qb = (b * 4096 + iw + l15) * 64 + g * 8;
        s8v qa00 = *(const s8v*)(qth + qb);
        s8v qa01 = *(const s8v*)(qtl + qb);
        s8v qa10 = *(const s8v*)(qth + qb + 32);
        s8v qa11 = *(const s8v*)(qtl + qb + 32);
        int irow = iw + g * 4;
        float4 m4 = *(const float4*)(mrow + b * 4096 + irow);
        float4 v4 = *(const float4*)(invl + b * 4096 + irow);
        float mr[4] = {m4.x, m4.y, m4.z, m4.w};
        float ivr[4] = {v4.x, v4.y, v4.z, v4.w};

        __syncthreads();   // previous iteration's P reads complete
#pragma unroll
        for (int js = 0; js < 4; ++js) {
            f4v acc = {0.f, 0.f, 0.f, 0.f};
            acc = MFMA16(qa00, kf[js][0][0], acc);
            acc = MFMA16(qa00, kf[js][0][1], acc);
            acc = MFMA16(qa01, kf[js][0][0], acc);
            acc = MFMA16(qa10, kf[js][1][0], acc);
            acc = MFMA16(qa10, kf[js][1][1], acc);
            acc = MFMA16(qa11, kf[js][1][0], acc);
            unsigned short hh[4], ll[4];
#pragma unroll
            for (int r = 0; r < 4; ++r) {
                float w = __expf(acc[r] - mr[r]) * ivr[r];
                split2(w, hh[r], ll[r]);
            }
            uint2 hv, lv;
            hv.x = hh[0] | ((unsigned int)hh[1] << 16);
            hv.y = hh[2] | ((unsigned int)hh[3] << 16);
            lv.x = ll[0] | ((unsigned int)ll[1] << 16);
            lv.y = ll[2] | ((unsigned int)ll[3] << 16);
            int row = js * 16 + l15, col = wv * 16 + g * 4;
            *(uint2*)&Ph[row][col] = hv;
            *(uint2*)&Pl[row][col] = lv;
        }
        __syncthreads();   // P tile ready
#pragma unroll
        for (int ic = 0; ic < 4; ++ic) {
            int n8 = (i0 >> 3) + ic * 4 + g;
            int va = (((b * 4 + cq) * 512 + n8) * 16 + l15) * 8;
            s8v ah = *(const s8v*)(vbh + va);
            s8v al = *(const s8v*)(vbl + va);
            int ilocal = ic * 32 + g * 8;
            s8v bh0 = *(const s8v*)&Ph[jh * 32 + l15][ilocal];
            s8v bl0 = *(const s8v*)&Pl[jh * 32 + l15][ilocal];
            oa = MFMA16(ah, bh0, oa);
            oa = MFMA16(ah, bl0, oa);
            oa = MFMA16(al, bh0, oa);
            s8v bh1 = *(const s8v*)&Ph[jh * 32 + 16 + l15][ilocal];
            s8v bl1 = *(const s8v*)&Pl[jh * 32 + 16 + l15][ilocal];
            ob = MFMA16(ah, bh1, ob);
            ob = MFMA16(ah, bl1, ob);
            ob = MFMA16(al, bh1, ob);
        }
    }
    int cb = b * 64 + cq * 16 + g * 4;
    int jb = j0 + jh * 32 + l15;
#pragma unroll
    for (int r = 0; r < 4; ++r) {
        pos[(cb + r) * 4096 + jb] = oa[r];
        pos[(cb + r) * 4096 + jb + 16] = ob[r];
    }
}

// ---------------- final: out = pg*pos + cg*(A@x) + 2*x (unchanged)
__global__ void k_final(const float* __restrict__ x, const float* __restrict__ pos,
                        const float* __restrict__ A, const float* __restrict__ pg,
                        const float* __restrict__ cg, float* __restrict__ out) {
    int n = blockIdx.x * 256 + threadIdx.x;
    int c = blockIdx.y, b = blockIdx.z;
    const float* Arow = A + (b * 64 + c) * 64;
    const float* xb = x + b * 64 * 4096;
    float acc = 0.0f;
#pragma unroll
    for (int d = 0; d < 64; ++d) acc += Arow[d] * xb[d * 4096 + n];
    float xc = xb[c * 4096 + n];
    float p = pos[(b * 64 + c) * 4096 + n];
    out[(b * 64 + c) * 4096 + n] = pg[0] * p + cg[0] * acc + 2.0f * xc;
}

extern "C" void kernel_launch(void* const* d_in, const int* in_sizes, int n_in,
                              void* d_out, int out_size, void* d_ws, size_t ws_size,
                              hipStream_t stream) {
    const float* x  = (const float*)d_in[0];
    const float* wq = (const float*)d_in[1];
    const float* bq = (const float*)d_in[2];
    const float* wk = (const float*)d_in[3];
    const float* bk = (const float*)d_in[4];
    const float* wv = (const float*)d_in[5];
    const float* bv = (const float*)d_in[6];
    const float* pg = (const float*)d_in[7];
    const float* cg = (const float*)d_in[8];
    float* out = (float*)d_out;

    if (ws_size < (size_t)WS_FLOATS * sizeof(float)) return;
    float* ws = (float*)d_ws;
    float* pos  = ws + OFF_POS;
    unsigned short* qth = (unsigned short*)(ws + OFF_QTH);
    unsigned short* qtl = (unsigned short*)(ws + OFF_QTL);
    unsigned short* kth = (unsigned short*)(ws + OFF_KTH);
    unsigned short* ktl = (unsigned short*)(ws + OFF_KTL);
    unsigned short* vbh = (unsigned short*)(ws + OFF_VBH);
    unsigned short* vbl = (unsigned short*)(ws + OFF_VBL);
    float* wt   = ws + OFF_WT;
    float* mp   = ws + OFF_MPART;
    float* lp   = ws + OFF_LPART;
    float* mrow = ws + OFF_M;
    float* invl = ws + OFF_INVL;
    float* Gp   = ws + OFF_GPART;
    float* A    = ws + OFF_A;

    k_wtrans<<<432, 256, 0, stream>>>(wq, wk, wv, wt);
    k_conv<<<dim3(64, 4, 3), 256, 0, stream>>>(x, wt, bq, bk, bv, qth, qtl, kth, ktl, vbh, vbl);
    k_gram<<<dim3(16, 4), 256, 0, stream>>>(x, Gp);
    k_asm<<<256, 64, 0, stream>>>(Gp, A);
    k_pass1<<<dim3(64, 4, 4), 256, 0, stream>>>(qth, qtl, kth, ktl, mp, lp);
    k_merge<<<64, 256, 0, stream>>>(mp, lp, mrow, invl);
    k_pass2<<<256, 512, 0, stream>>>(qth, qtl, kth, ktl, vbh, vbl, mrow, invl, pos);
    k_final<<<dim3(16, 64, 4), 256, 0, stream>>>(x, pos, A, pg, cg, out);
}